// Round 2
// baseline (679.010 us; speedup 1.0000x reference)
//
#include <hip/hip_runtime.h>
#include <hip/hip_bf16.h>

#define N_V   50000
#define KTOT  2624        // 41*64
#define NOUT  512         // O*T
#define NKB   41
#define BM    128
#define BN    256

typedef short v8s __attribute__((ext_vector_type(8)));
typedef float v4f __attribute__((ext_vector_type(4)));
typedef unsigned int v4u __attribute__((ext_vector_type(4)));
typedef unsigned short u16;
typedef unsigned int u32;

__device__ __forceinline__ u16 f2bf(float f) {
    u32 u = __float_as_uint(f);
    return (u16)((u + 0x7FFFu + ((u >> 16) & 1u)) >> 16);   // RNE
}

// ---------- kernel 1: mesh_signal fp32 -> bf16 ----------
__global__ void cast_ms(const float* __restrict__ ms, u16* __restrict__ msb) {
    int i = (blockIdx.x * 256 + threadIdx.x) * 4;
    float4 v = *reinterpret_cast<const float4*>(ms + i);
    ushort4 o;
    o.x = f2bf(v.x); o.y = f2bf(v.y); o.z = f2bf(v.z); o.w = f2bf(v.w);
    *reinterpret_cast<ushort4*>(msb + i) = o;
}

// ---------- kernel 2: combined weights, flat (one thread per element) ----------
__global__ void build_w2(const float* __restrict__ nw, const float* __restrict__ cw,
                         const float* __restrict__ coeff, u16* __restrict__ w2) {
    int l = blockIdx.x * 256 + threadIdx.x;
    if (l >= NOUT * KTOT) return;
    int j = l / KTOT, k = l - j * KTOT;
    int o = j >> 6, t = j & 63;
    u16 v;
    if (k >= 2560) {
        v = f2bf(cw[t * 64 + (k - 2560)]);
    } else {
        int m = k >> 6, c = k & 63;
        float s = 0.f;
        #pragma unroll
        for (int ra = 0; ra < 40; ++ra) {
            int r = ra >> 3, a = ra & 7;
            s += coeff[ra * 40 + m] * nw[((t * 5 + r) * 8 + ((a + o) & 7)) * 64 + c];
        }
        v = f2bf(s);
    }
    w2[l] = v;
}

// async global->LDS, 16 B per lane; LDS dst = wave-uniform base + lane*16
__device__ __forceinline__ void gl2lds(const u16* g, u16* l) {
    __builtin_amdgcn_global_load_lds(
        (const __attribute__((address_space(1))) u32*)(uintptr_t)g,
        (__attribute__((address_space(3))) u32*)(uintptr_t)l, 16, 0, 0);
}

// ---------- kernel 3: fused patch-operator + GEMM, software-pipelined ----------
__global__ __launch_bounds__(512, 4)
void gemm_fused(const float* __restrict__ bary, const u16* __restrict__ msb,
                const u16* __restrict__ w2, const float* __restrict__ bias,
                float* __restrict__ out) {
    __shared__ u16 At[BM * 64];          // 16 KB, XOR-swizzled 16B blocks
    __shared__ u16 Bt[2 * BN * 64];      // 2 x 32 KB, XOR-swizzled

    const int tid  = threadIdx.x;
    const int lane = tid & 63, wave = tid >> 6;
    const int l15  = lane & 15, q = lane >> 4;
    const int wm   = wave >> 2, wn = wave & 3;

    const int id  = blockIdx.x;
    const int bx  = id % 391, by = id / 391;   // temporal split: all XCDs on one w2 half
    const int row0 = bx * BM, col0 = by * BN;

    // A-build mapping: thread -> (row ar, 16-elem slab)
    const int ar  = tid >> 2;
    const u32 acb = (u32)(tid & 3) * 32;       // byte offset within 128-B msb row
    int an = row0 + ar; if (an > N_V - 1) an = N_V - 1;
    const u32* brow = (const u32*)bary + (size_t)an * 240;
    const u32 an_off = (u32)an * 128 + acb;    // center-chunk source

    // At store offsets (swizzled): row ar, blocks 2*(tid&3), +1
    const int e_a = ar & 7;
    const u32 at_w0 = (u32)ar * 128 + (u32)(((2 * (tid & 3)) ^ e_a) * 16);
    const u32 at_w1 = at_w0 ^ 16;

    // fragment read offsets (s=1 is ^64)
    const int eq = l15 & 7;
    const u32 a_rd0 = (u32)(wm * 64 + l15) * 128 + (u32)((q ^ eq) * 16);
    const u32 b_rd0 = (u32)(wn * 64 + l15) * 128 + (u32)((q ^ eq) * 16);

    // B staging: lane covers row (w_eff*8 + lane/8), swizzled block (lane&7)^(lane/8)
    const int rl = lane >> 3;
    const int bl = (lane & 7) ^ rl;

    v4f acc[4][4];
    #pragma unroll
    for (int mi = 0; mi < 4; ++mi)
        #pragma unroll
        for (int ni = 0; ni < 4; ++ni)
            acc[mi][ni] = (v4f){0.f, 0.f, 0.f, 0.f};

    v4u g0a, g0b, g1a, g1b, g2a, g2b;   // gather prefetch (chunk kb)
    v4u blo, bhi;                        // raw bary words (chunk kb+1)
    float w0c, w1c, w2c;                 // weights for current chunk

    auto issue_gathers = [&](u32 o0, u32 o1, u32 o2) {
        const char* mb = (const char*)msb;
        g0a = *(const v4u*)(mb + o0); g0b = *(const v4u*)(mb + o0 + 16);
        g1a = *(const v4u*)(mb + o1); g1b = *(const v4u*)(mb + o1 + 16);
        g2a = *(const v4u*)(mb + o2); g2b = *(const v4u*)(mb + o2 + 16);
    };
    auto bary_load = [&](int kc) {   // 24-B record via 2 aligned 16-B loads
        u32 d0 = ((u32)(kc * 6)) & ~3u;
        blo = *(const v4u*)(brow + d0);
        bhi = *(const v4u*)(brow + d0 + 4);
    };
    auto decode_issue = [&](int kc) {  // decode chunk kc from blo/bhi, issue its gathers
        u32 uf0, uw0, uf1, uw1, uf2, uw2;
        if (kc & 1) { uf0 = blo[2]; uw0 = blo[3]; uf1 = bhi[0]; uw1 = bhi[1]; uf2 = bhi[2]; uw2 = bhi[3]; }
        else        { uf0 = blo[0]; uw0 = blo[1]; uf1 = blo[2]; uw1 = blo[3]; uf2 = bhi[0]; uw2 = bhi[1]; }
        u32 o0 = ((u32)(int)__uint_as_float(uf0) << 7) + acb;
        u32 o1 = ((u32)(int)__uint_as_float(uf1) << 7) + acb;
        u32 o2 = ((u32)(int)__uint_as_float(uf2) << 7) + acb;
        issue_gathers(o0, o1, o2);
        w0c = __uint_as_float(uw0); w1c = __uint_as_float(uw1); w2c = __uint_as_float(uw2);
    };
    auto ipair = [&](u32 pa, u32 pb, u32 pc) -> u32 {
        float a0 = __uint_as_float(pa << 16), a1 = __uint_as_float(pa & 0xffff0000u);
        float b0 = __uint_as_float(pb << 16), b1 = __uint_as_float(pb & 0xffff0000u);
        float c0 = __uint_as_float(pc << 16), c1 = __uint_as_float(pc & 0xffff0000u);
        float r0 = w0c * a0 + w1c * b0 + w2c * c0;
        float r1 = w0c * a1 + w1c * b1 + w2c * c1;
        return __builtin_amdgcn_perm(__float_as_uint(r1) + 0x8000u,
                                     __float_as_uint(r0) + 0x8000u, 0x07060302u);
    };
    auto blds = [&](int kb_ld, int buf) {   // 4 async 16B/lane DMA issues
        #pragma unroll
        for (int i = 0; i < 4; ++i) {
            int w_eff = wave * 4 + i;
            u32 src = (u32)(col0 + w_eff * 8 + rl) * KTOT + (u32)kb_ld * 64 + (u32)(bl * 8);
            gl2lds(w2 + src, &Bt[buf * (BN * 64) + w_eff * 512]);
        }
    };
    auto mfma_step = [&](int buf) {
        const char* atp = (const char*)At;
        const char* btp = (const char*)Bt + buf * (BN * 64 * 2);
        #pragma unroll
        for (int s = 0; s < 2; ++s) {
            u32 ao = a_rd0 ^ (u32)(s * 64), bo = b_rd0 ^ (u32)(s * 64);
            v8s a_f[4], b_f[4];
            #pragma unroll
            for (int mi = 0; mi < 4; ++mi) a_f[mi] = *(const v8s*)(atp + ao + mi * 2048);
            #pragma unroll
            for (int ni = 0; ni < 4; ++ni) b_f[ni] = *(const v8s*)(btp + bo + ni * 2048);
            #pragma unroll
            for (int mi = 0; mi < 4; ++mi)
                #pragma unroll
                for (int ni = 0; ni < 4; ++ni)
                    acc[mi][ni] = __builtin_amdgcn_mfma_f32_16x16x32_bf16(
                        a_f[mi], b_f[ni], acc[mi][ni], 0, 0, 0);
        }
    };

    // ---- prologue: fill pipeline for kb=0 ----
    bary_load(0);          // waits (one-time)
    decode_issue(0);       // 6 gather issues for chunk 0
    bary_load(1);          // 2 issues (chunk 1 record, in flight)
    blds(0, 0);            // 4 DMA issues

    v4u cv0, cv1;
    #pragma unroll 1
    for (int kb = 0; kb < NKB; ++kb) {
        // convert current gathers (register-only; waits on prefetched loads)
        if (kb < 40) {
            #pragma unroll
            for (int j = 0; j < 4; ++j) {
                cv0[j] = ipair(g0a[j], g1a[j], g2a[j]);
                cv1[j] = ipair(g0b[j], g1b[j], g2b[j]);
            }
        } else { cv0 = (v4u)g0a; cv1 = (v4u)g0b; }

        // issue next-iteration prefetches (VGPR dests; no LDS hazard -> pre-barrier)
        if (kb <= 37)      { decode_issue(kb + 1); bary_load(kb + 2); }  // 6 + 2
        else if (kb == 38) { decode_issue(39); }                          // 6
        else if (kb == 39) {                                              // center chunk: 2
            g0a = *(const v4u*)((const char*)msb + an_off);
            g0b = *(const v4u*)((const char*)msb + an_off + 16);
        }

        // barrier1: previous MFMA's LDS reads are done in all waves
        asm volatile("s_barrier" ::: "memory");

        if (kb <= 39) blds(kb + 1, (kb + 1) & 1);   // 4 DMA issues into other buffer

        *(v4u*)((char*)At + at_w0) = cv0;
        *(v4u*)((char*)At + at_w1) = cv1;

        // barrier2: drain exactly down to this iteration's prefetches (in-order vmcnt);
        // guarantees B_lds(kb) + At writes are visible, keeps 12/10/6 loads in flight.
        if (kb <= 37)      asm volatile("s_waitcnt vmcnt(12) lgkmcnt(0)\ns_barrier" ::: "memory");
        else if (kb == 38) asm volatile("s_waitcnt vmcnt(10) lgkmcnt(0)\ns_barrier" ::: "memory");
        else if (kb == 39) asm volatile("s_waitcnt vmcnt(6) lgkmcnt(0)\ns_barrier" ::: "memory");
        else               asm volatile("s_waitcnt vmcnt(0) lgkmcnt(0)\ns_barrier" ::: "memory");

        mfma_step(kb & 1);
    }

    // ---- epilogue: bias + relu + masked store ----
    float bv[4];
    #pragma unroll
    for (int ni = 0; ni < 4; ++ni) bv[ni] = bias[ni * 16 + l15];
    #pragma unroll
    for (int mi = 0; mi < 4; ++mi) {
        int rbase = row0 + wm * 64 + mi * 16 + q * 4;
        #pragma unroll
        for (int ni = 0; ni < 4; ++ni) {
            int cg = col0 + wn * 64 + ni * 16 + l15;
            #pragma unroll
            for (int rg = 0; rg < 4; ++rg) {
                int rr = rbase + rg;
                if (rr < N_V) {
                    float v = acc[mi][ni][rg] + bv[ni];
                    out[(size_t)rr * NOUT + cg] = v > 0.f ? v : 0.f;
                }
            }
        }
    }
}

extern "C" void kernel_launch(void* const* d_in, const int* in_sizes, int n_in,
                              void* d_out, int out_size, void* d_ws, size_t ws_size,
                              hipStream_t stream) {
    const float* ms    = (const float*)d_in[0];
    const float* bary  = (const float*)d_in[1];
    const float* nw    = (const float*)d_in[2];
    const float* cw    = (const float*)d_in[3];
    const float* bias  = (const float*)d_in[4];
    const float* coeff = (const float*)d_in[5];
    float* out = (float*)d_out;

    u16* msb = (u16*)d_ws;                        // 6,400,000 B
    u16* w2  = (u16*)((char*)d_ws + 6400000);     // 2,686,976 B

    cast_ms<<<3125, 256, 0, stream>>>(ms, msb);
    build_w2<<<(NOUT * KTOT + 255) / 256, 256, 0, stream>>>(nw, cw, coeff, w2);
    gemm_fused<<<782, 512, 0, stream>>>(bary, msb, w2, bias, out);
}

// Round 3
// 462.034 us; speedup vs baseline: 1.4696x; 1.4696x over previous
//
#include <hip/hip_runtime.h>
#include <hip/hip_bf16.h>

#define N_V   50000
#define KTOT  2624        // 41*64
#define NOUT  512         // O*T
#define NKB   41
#define BM    128
#define BN    256

typedef short v8s __attribute__((ext_vector_type(8)));
typedef float v4f __attribute__((ext_vector_type(4)));
typedef unsigned int v4u __attribute__((ext_vector_type(4)));
typedef unsigned short u16;
typedef unsigned int u32;

__device__ __forceinline__ u16 f2bf(float f) {
    u32 u = __float_as_uint(f);
    return (u16)((u + 0x7FFFu + ((u >> 16) & 1u)) >> 16);   // RNE
}

// ---------- kernel 1: mesh_signal fp32 -> bf16 ----------
__global__ void cast_ms(const float* __restrict__ ms, u16* __restrict__ msb) {
    int i = (blockIdx.x * 256 + threadIdx.x) * 4;
    float4 v = *reinterpret_cast<const float4*>(ms + i);
    ushort4 o;
    o.x = f2bf(v.x); o.y = f2bf(v.y); o.z = f2bf(v.z); o.w = f2bf(v.w);
    *reinterpret_cast<ushort4*>(msb + i) = o;
}

// ---------- kernel 2: combined weights (512 x 2624 bf16) ----------
__global__ void build_w2(const float* __restrict__ nw, const float* __restrict__ cw,
                         const float* __restrict__ coeff, u16* __restrict__ w2) {
    int l = blockIdx.x * 256 + threadIdx.x;
    if (l >= NOUT * KTOT) return;
    int j = l / KTOT, k = l - j * KTOT;
    int o = j >> 6, t = j & 63;
    u16 v;
    if (k >= 2560) {
        v = f2bf(cw[t * 64 + (k - 2560)]);
    } else {
        int m = k >> 6, c = k & 63;
        float s = 0.f;
        #pragma unroll
        for (int ra = 0; ra < 40; ++ra) {
            int r = ra >> 3, a = ra & 7;
            s += coeff[ra * 40 + m] * nw[((t * 5 + r) * 8 + ((a + o) & 7)) * 64 + c];
        }
        v = f2bf(s);
    }
    w2[l] = v;
}

__device__ __forceinline__ void gl2lds(const u16* g, u16* l) {
    __builtin_amdgcn_global_load_lds(
        (const __attribute__((address_space(1))) u32*)(uintptr_t)g,
        (__attribute__((address_space(3))) u32*)(uintptr_t)l, 16, 0, 0);
}

__device__ __forceinline__ u32 ipair(u32 pa, u32 pb, u32 pc, float w0, float w1, float w2) {
    float a0 = __uint_as_float(pa << 16), a1 = __uint_as_float(pa & 0xffff0000u);
    float b0 = __uint_as_float(pb << 16), b1 = __uint_as_float(pb & 0xffff0000u);
    float c0 = __uint_as_float(pc << 16), c1 = __uint_as_float(pc & 0xffff0000u);
    float r0 = w0 * a0 + w1 * b0 + w2 * c0;
    float r1 = w0 * a1 + w1 * b1 + w2 * c1;
    return __builtin_amdgcn_perm(__float_as_uint(r1) + 0x8000u,
                                 __float_as_uint(r0) + 0x8000u, 0x07060302u);
}

// ---------- kernel 3: fused patch-operator + GEMM, depth-2 register pipeline ----------
__global__ __launch_bounds__(512, 2)
void gemm_fused(const float* __restrict__ bary, const u16* __restrict__ msb,
                const u16* __restrict__ w2, const float* __restrict__ bias,
                float* __restrict__ out) {
    __shared__ u16 At[BM * 64];          // 16 KB, XOR-swizzled 16B blocks
    __shared__ u16 Bt[2 * BN * 64];      // 2 x 32 KB, XOR-swizzled

    const int tid  = threadIdx.x;
    const int lane = tid & 63, wave = tid >> 6;
    const int l15  = lane & 15, q = lane >> 4;
    const int wm   = wave >> 2, wn = wave & 3;

    const int id  = blockIdx.x;
    const int bx  = id % 391, by = id / 391;
    const int row0 = bx * BM, col0 = by * BN;

    const int ar  = tid >> 2;
    const u32 acb = (u32)(tid & 3) * 32;
    int an = row0 + ar; if (an > N_V - 1) an = N_V - 1;
    const u32* brow = (const u32*)bary + (size_t)an * 240;
    const u32 an_off = (u32)an * 128 + acb;

    const int e_a = ar & 7;
    const u32 at_w0 = (u32)ar * 128 + (u32)(((2 * (tid & 3)) ^ e_a) * 16);
    const u32 at_w1 = at_w0 ^ 16;

    const int eq = l15 & 7;
    const u32 a_rd0 = (u32)(wm * 64 + l15) * 128 + (u32)((q ^ eq) * 16);
    const u32 b_rd0 = (u32)(wn * 64 + l15) * 128 + (u32)((q ^ eq) * 16);

    const int rl = lane >> 3;
    const int bl = (lane & 7) ^ rl;

    v4f acc[4][4];
    #pragma unroll
    for (int mi = 0; mi < 4; ++mi)
        #pragma unroll
        for (int ni = 0; ni < 4; ++ni)
            acc[mi][ni] = (v4f){0.f, 0.f, 0.f, 0.f};

    // pipeline state: parity-0 and parity-1 register sets (statically indexed)
    v4u G0_0a, G0_0b, G0_1a, G0_1b, G0_2a, G0_2b;
    v4u G1_0a, G1_0b, G1_1a, G1_1b, G1_2a, G1_2b;
    v4u B0lo, B0hi, B1lo, B1hi;
    float w00, w01, w02, w10, w11, w12;
    v4u cv0, cv1;

#define BARY_LOAD(DLO, DHI, kc) do { \
    u32 _d0 = ((u32)((kc) * 6)) & ~3u; \
    DLO = *(const v4u*)(brow + _d0); \
    DHI = *(const v4u*)(brow + _d0 + 4); } while (0)

#define DECODE_ISSUE(PAR, BLO, BHI, Ga0, Gb0, Ga1, Gb1, Ga2, Gb2, W0, W1, W2) do { \
    u32 uf0, uw0, uf1, uw1, uf2, uw2; \
    if (PAR) { uf0 = BLO[2]; uw0 = BLO[3]; uf1 = BHI[0]; uw1 = BHI[1]; uf2 = BHI[2]; uw2 = BHI[3]; } \
    else     { uf0 = BLO[0]; uw0 = BLO[1]; uf1 = BLO[2]; uw1 = BLO[3]; uf2 = BHI[0]; uw2 = BHI[1]; } \
    u32 _o0 = ((u32)(int)__uint_as_float(uf0) << 7) + acb; \
    u32 _o1 = ((u32)(int)__uint_as_float(uf1) << 7) + acb; \
    u32 _o2 = ((u32)(int)__uint_as_float(uf2) << 7) + acb; \
    const char* _mb = (const char*)msb; \
    Ga0 = *(const v4u*)(_mb + _o0); Gb0 = *(const v4u*)(_mb + _o0 + 16); \
    Ga1 = *(const v4u*)(_mb + _o1); Gb1 = *(const v4u*)(_mb + _o1 + 16); \
    Ga2 = *(const v4u*)(_mb + _o2); Gb2 = *(const v4u*)(_mb + _o2 + 16); \
    W0 = __uint_as_float(uw0); W1 = __uint_as_float(uw1); W2 = __uint_as_float(uw2); } while (0)

#define CONVERT(Ga0, Gb0, Ga1, Gb1, Ga2, Gb2, W0, W1, W2) do { \
    _Pragma("unroll") \
    for (int _j = 0; _j < 4; ++_j) { \
        cv0[_j] = ipair(Ga0[_j], Ga1[_j], Ga2[_j], W0, W1, W2); \
        cv1[_j] = ipair(Gb0[_j], Gb1[_j], Gb2[_j], W0, W1, W2); } } while (0)

#define BLDS(KB_LD, BUF) do { \
    _Pragma("unroll") \
    for (int _ii = 0; _ii < 4; ++_ii) { \
        int _we = wave * 4 + _ii; \
        u32 _src = (u32)(col0 + _we * 8 + rl) * KTOT + (u32)(KB_LD) * 64 + (u32)(bl * 8); \
        gl2lds(w2 + _src, &Bt[(BUF) * (BN * 64) + _we * 512]); } } while (0)

#define AT_STORE() do { \
    *(v4u*)((char*)At + at_w0) = cv0; \
    *(v4u*)((char*)At + at_w1) = cv1; } while (0)

#define MFMA_STEP(BUF) do { \
    const char* _atp = (const char*)At; \
    const char* _btp = (const char*)Bt + (BUF) * (BN * 64 * 2); \
    _Pragma("unroll") \
    for (int _s = 0; _s < 2; ++_s) { \
        u32 _ao = a_rd0 ^ (u32)(_s * 64), _bo = b_rd0 ^ (u32)(_s * 64); \
        v8s _af[4], _bf[4]; \
        _Pragma("unroll") \
        for (int _mi = 0; _mi < 4; ++_mi) _af[_mi] = *(const v8s*)(_atp + _ao + _mi * 2048); \
        _Pragma("unroll") \
        for (int _ni = 0; _ni < 4; ++_ni) _bf[_ni] = *(const v8s*)(_btp + _bo + _ni * 2048); \
        _Pragma("unroll") \
        for (int _mi = 0; _mi < 4; ++_mi) \
            _Pragma("unroll") \
            for (int _ni = 0; _ni < 4; ++_ni) \
                acc[_mi][_ni] = __builtin_amdgcn_mfma_f32_16x16x32_bf16( \
                    _af[_mi], _bf[_ni], acc[_mi][_ni], 0, 0, 0); } } while (0)

#define BAR2_12() asm volatile("s_waitcnt vmcnt(12) lgkmcnt(0)\ns_barrier" ::: "memory")
#define BAR2_10() asm volatile("s_waitcnt vmcnt(10) lgkmcnt(0)\ns_barrier" ::: "memory")
#define BAR2_6()  asm volatile("s_waitcnt vmcnt(6) lgkmcnt(0)\ns_barrier"  ::: "memory")
#define BAR2_4()  asm volatile("s_waitcnt vmcnt(4) lgkmcnt(0)\ns_barrier"  ::: "memory")
#define BAR2_0()  asm volatile("s_waitcnt vmcnt(0) lgkmcnt(0)\ns_barrier"  ::: "memory")
#define BAR1()    asm volatile("s_barrier" ::: "memory")

    // ---- prologue: fill depth-2 pipeline ----
    BARY_LOAD(B0lo, B0hi, 0);
    DECODE_ISSUE(0, B0lo, B0hi, G0_0a, G0_0b, G0_1a, G0_1b, G0_2a, G0_2b, w00, w01, w02); // gathers(0)
    BARY_LOAD(B1lo, B1hi, 1);
    DECODE_ISSUE(1, B1lo, B1hi, G1_0a, G1_0b, G1_1a, G1_1b, G1_2a, G1_2b, w10, w11, w12); // gathers(1)
    BARY_LOAD(B0lo, B0hi, 2);   // record 2
    BLDS(0, 0);

    // ---- main loop: kb = 0..39 as 20 even/odd pairs ----
    #pragma unroll 1
    for (int i = 0; i < 20; ++i) {
        {   // kb even (parity 0)
            const int kb = 2 * i;
            CONVERT(G0_0a, G0_0b, G0_1a, G0_1b, G0_2a, G0_2b, w00, w01, w02);
            if (kb <= 36) BARY_LOAD(B1lo, B1hi, kb + 3);                 // odd record -> buf1
            if (kb <= 37) {
                DECODE_ISSUE(0, B0lo, B0hi, G0_0a, G0_0b, G0_1a, G0_1b, G0_2a, G0_2b,
                             w00, w01, w02);                             // gathers(kb+2)
            } else if (kb == 38) {                                       // center chunk (40)
                G0_0a = *(const v4u*)((const char*)msb + an_off);
                G0_0b = *(const v4u*)((const char*)msb + an_off + 16);
            }
            BAR1();
            BLDS(kb + 1, 1);
            AT_STORE();
            if (kb <= 36) BAR2_12(); else BAR2_6();                      // kb==38 -> 6
            MFMA_STEP(0);
        }
        {   // kb odd (parity 1)
            const int kb = 2 * i + 1;
            CONVERT(G1_0a, G1_0b, G1_1a, G1_1b, G1_2a, G1_2b, w10, w11, w12);
            if (kb <= 36) BARY_LOAD(B0lo, B0hi, kb + 3);                 // even record -> buf0
            if (kb <= 37)
                DECODE_ISSUE(1, B1lo, B1hi, G1_0a, G1_0b, G1_1a, G1_1b, G1_2a, G1_2b,
                             w10, w11, w12);
            BAR1();
            BLDS(kb + 1, 0);
            AT_STORE();
            if (kb <= 36) BAR2_12();
            else if (kb == 37) BAR2_10();
            else BAR2_4();                                               // kb==39
            MFMA_STEP(1);
        }
    }
    // ---- final iteration kb = 40 (center chunk, parity 0) ----
    {
        cv0 = G0_0a; cv1 = G0_0b;    // already bf16
        BAR1();
        AT_STORE();
        BAR2_0();
        MFMA_STEP(0);
    }

    // ---- epilogue: bias + relu + masked store ----
    float bv[4];
    #pragma unroll
    for (int ni = 0; ni < 4; ++ni) bv[ni] = bias[ni * 16 + l15];
    #pragma unroll
    for (int mi = 0; mi < 4; ++mi) {
        int rbase = row0 + wm * 64 + mi * 16 + q * 4;
        #pragma unroll
        for (int ni = 0; ni < 4; ++ni) {
            int cg = col0 + wn * 64 + ni * 16 + l15;
            #pragma unroll
            for (int rg = 0; rg < 4; ++rg) {
                int rr = rbase + rg;
                if (rr < N_V) {
                    float v = acc[mi][ni][rg] + bv[ni];
                    out[(size_t)rr * NOUT + cg] = v > 0.f ? v : 0.f;
                }
            }
        }
    }
}

extern "C" void kernel_launch(void* const* d_in, const int* in_sizes, int n_in,
                              void* d_out, int out_size, void* d_ws, size_t ws_size,
                              hipStream_t stream) {
    const float* ms    = (const float*)d_in[0];
    const float* bary  = (const float*)d_in[1];
    const float* nw    = (const float*)d_in[2];
    const float* cw    = (const float*)d_in[3];
    const float* bias  = (const float*)d_in[4];
    const float* coeff = (const float*)d_in[5];
    float* out = (float*)d_out;

    u16* msb = (u16*)d_ws;                        // 6,400,000 B
    u16* w2  = (u16*)((char*)d_ws + 6400000);     // 2,686,976 B

    cast_ms<<<3125, 256, 0, stream>>>(ms, msb);
    build_w2<<<(NOUT * KTOT + 255) / 256, 256, 0, stream>>>(nw, cw, coeff, w2);
    gemm_fused<<<782, 512, 0, stream>>>(bary, msb, w2, bias, out);
}

// Round 4
// 449.908 us; speedup vs baseline: 1.5092x; 1.0270x over previous
//
#include <hip/hip_runtime.h>
#include <hip/hip_bf16.h>

#define N_V   50000
#define KTOT  2624        // 41*64
#define NOUT  512         // O*T
#define NKB   41
#define BM    128
#define BN    256

typedef short v8s __attribute__((ext_vector_type(8)));
typedef float v4f __attribute__((ext_vector_type(4)));
typedef unsigned int v4u __attribute__((ext_vector_type(4)));
typedef unsigned short u16;
typedef unsigned int u32;

__device__ __forceinline__ u16 f2bf(float f) {
    u32 u = __float_as_uint(f);
    return (u16)((u + 0x7FFFu + ((u >> 16) & 1u)) >> 16);   // RNE
}

__device__ __forceinline__ void gl2lds(const u16* g, u16* l) {
    __builtin_amdgcn_global_load_lds(
        (const __attribute__((address_space(1))) u32*)(uintptr_t)g,
        (__attribute__((address_space(3))) u32*)(uintptr_t)l, 16, 0, 0);
}

__device__ __forceinline__ u32 ipair(u32 pa, u32 pb, u32 pc, float w0, float w1, float w2) {
    float a0 = __uint_as_float(pa << 16), a1 = __uint_as_float(pa & 0xffff0000u);
    float b0 = __uint_as_float(pb << 16), b1 = __uint_as_float(pb & 0xffff0000u);
    float c0 = __uint_as_float(pc << 16), c1 = __uint_as_float(pc & 0xffff0000u);
    float r0 = w0 * a0 + w1 * b0 + w2 * c0;
    float r1 = w0 * a1 + w1 * b1 + w2 * c1;
    return __builtin_amdgcn_perm(__float_as_uint(r1) + 0x8000u,
                                 __float_as_uint(r0) + 0x8000u, 0x07060302u);
}

// ---------- kernel 1: mesh_signal fp32 -> bf16 (+ optional X center columns) ----------
__global__ void cast_ms(const float* __restrict__ ms, u16* __restrict__ msb,
                        u16* __restrict__ Xc) {
    int i = (blockIdx.x * 256 + threadIdx.x) * 4;
    float4 v = *reinterpret_cast<const float4*>(ms + i);
    ushort4 o;
    o.x = f2bf(v.x); o.y = f2bf(v.y); o.z = f2bf(v.z); o.w = f2bf(v.w);
    *reinterpret_cast<ushort4*>(msb + i) = o;
    if (Xc) {
        int n = i >> 6, c = i & 63;
        *reinterpret_cast<ushort4*>(Xc + (size_t)n * KTOT + 2560 + c) = o;
    }
}

// ---------- kernel 2: combined weights (512 x 2624 bf16) ----------
__global__ void build_w2(const float* __restrict__ nw, const float* __restrict__ cw,
                         const float* __restrict__ coeff, u16* __restrict__ w2) {
    int l = blockIdx.x * 256 + threadIdx.x;
    if (l >= NOUT * KTOT) return;
    int j = l / KTOT, k = l - j * KTOT;
    int o = j >> 6, t = j & 63;
    u16 v;
    if (k >= 2560) {
        v = f2bf(cw[t * 64 + (k - 2560)]);
    } else {
        int m = k >> 6, c = k & 63;
        float s = 0.f;
        #pragma unroll
        for (int ra = 0; ra < 40; ++ra) {
            int r = ra >> 3, a = ra & 7;
            s += coeff[ra * 40 + m] * nw[((t * 5 + r) * 8 + ((a + o) & 7)) * 64 + c];
        }
        v = f2bf(s);
    }
    w2[l] = v;
}

// ---------- kernel 3: materialize X (patch operator), dup=1, full occupancy ----------
// thread t -> (n = t/160, m = (t%160)/4, j = t&3): 32 B of X[n][m*64 + j*16..]
__global__ void build_x(const float* __restrict__ bary, const u16* __restrict__ msb,
                        u16* __restrict__ X) {
    u32 t = blockIdx.x * 256 + threadIdx.x;       // 8,000,000 exact
    u32 n = t / 160u;
    u32 rem = t - n * 160u;
    u32 m = rem >> 2, j = rem & 3;
    const float* bb = bary + (size_t)n * 240 + m * 6;
    float2 p0 = *(const float2*)(bb);
    float2 p1 = *(const float2*)(bb + 2);
    float2 p2 = *(const float2*)(bb + 4);
    u32 jb = j * 32u;
    u32 o0 = ((u32)(int)p0.x) * 128u + jb;
    u32 o1 = ((u32)(int)p1.x) * 128u + jb;
    u32 o2 = ((u32)(int)p2.x) * 128u + jb;
    const char* mb = (const char*)msb;
    v4u a0 = *(const v4u*)(mb + o0), b0 = *(const v4u*)(mb + o0 + 16);
    v4u a1 = *(const v4u*)(mb + o1), b1 = *(const v4u*)(mb + o1 + 16);
    v4u a2 = *(const v4u*)(mb + o2), b2 = *(const v4u*)(mb + o2 + 16);
    v4u c0, c1;
    #pragma unroll
    for (int e = 0; e < 4; ++e) {
        c0[e] = ipair(a0[e], a1[e], a2[e], p0.y, p1.y, p2.y);
        c1[e] = ipair(b0[e], b1[e], b2[e], p0.y, p1.y, p2.y);
    }
    char* xp = (char*)X + (size_t)n * (KTOT * 2) + m * 128 + jb;
    *(v4u*)xp = c0;
    *(v4u*)(xp + 16) = c1;
}

// ---------- kernel 4: clean GEMM out = relu(X * w2^T + bias), m97 structure ----------
__global__ __launch_bounds__(512, 4)
void gemm2(const u16* __restrict__ X, const u16* __restrict__ w2,
           const float* __restrict__ bias, float* __restrict__ out) {
    __shared__ u16 At[BM * 64];     // 16 KB, XOR-swizzled 16B blocks
    __shared__ u16 Bt[BN * 64];     // 32 KB, XOR-swizzled

    const int tid  = threadIdx.x;
    const int lane = tid & 63, wave = tid >> 6;
    const int l15  = lane & 15, q = lane >> 4;
    const int wm   = wave >> 2, wn = wave & 3;

    // pair-mapping: ids k and k^8 share an XCD (xcd = id % 8) -> X panel L2 reuse
    const int id = blockIdx.x;
    const int p  = (id & 7) + 8 * (id >> 4);
    const int by = (id >> 3) & 1;
    if (p >= 391) return;
    const int row0 = p * BM, col0 = by * BN;

    // A DMA: 2 issues/thread; LDS slot = wave*128 + h*64 + lane (16B units)
    u32 aoff[2];
    #pragma unroll
    for (int h = 0; h < 2; ++h) {
        int slot = wave * 128 + h * 64 + lane;
        int arow = slot >> 3, ablk = (slot & 7) ^ (arow & 7);
        int grow = row0 + arow; if (grow > N_V - 1) grow = N_V - 1;
        aoff[h] = (u32)grow * (u32)KTOT + (u32)(ablk * 8);
    }
    // B DMA: 4 issues/thread; LDS slot = wave*256 + i*64 + lane
    u32 boff[4];
    #pragma unroll
    for (int i = 0; i < 4; ++i) {
        int slot = wave * 256 + i * 64 + lane;
        int brow = slot >> 3, bblk = (slot & 7) ^ (brow & 7);
        boff[i] = (u32)(col0 + brow) * (u32)KTOT + (u32)(bblk * 8);
    }

    const int eq = l15 & 7;
    const u32 a_rd0 = (u32)(wm * 64 + l15) * 128 + (u32)((q ^ eq) * 16);
    const u32 b_rd0 = (u32)(wn * 64 + l15) * 128 + (u32)((q ^ eq) * 16);

    v4f acc[4][4];
    #pragma unroll
    for (int mi = 0; mi < 4; ++mi)
        #pragma unroll
        for (int ni = 0; ni < 4; ++ni)
            acc[mi][ni] = (v4f){0.f, 0.f, 0.f, 0.f};

    #pragma unroll 1
    for (int kb = 0; kb < NKB; ++kb) {
        __syncthreads();
        #pragma unroll
        for (int h = 0; h < 2; ++h)
            gl2lds(X + aoff[h] + kb * 64, &At[wave * 1024 + h * 512]);
        #pragma unroll
        for (int i = 0; i < 4; ++i)
            gl2lds(w2 + boff[i] + kb * 64, &Bt[wave * 2048 + i * 512]);
        __syncthreads();

        const char* atp = (const char*)At;
        const char* btp = (const char*)Bt;
        #pragma unroll
        for (int s = 0; s < 2; ++s) {
            u32 ao = a_rd0 ^ (u32)(s * 64), bo = b_rd0 ^ (u32)(s * 64);
            v8s a_f[4], b_f[4];
            #pragma unroll
            for (int mi = 0; mi < 4; ++mi) a_f[mi] = *(const v8s*)(atp + ao + mi * 2048);
            #pragma unroll
            for (int ni = 0; ni < 4; ++ni) b_f[ni] = *(const v8s*)(btp + bo + ni * 2048);
            #pragma unroll
            for (int mi = 0; mi < 4; ++mi)
                #pragma unroll
                for (int ni = 0; ni < 4; ++ni)
                    acc[mi][ni] = __builtin_amdgcn_mfma_f32_16x16x32_bf16(
                        a_f[mi], b_f[ni], acc[mi][ni], 0, 0, 0);
        }
    }

    float bv[4];
    #pragma unroll
    for (int ni = 0; ni < 4; ++ni) bv[ni] = bias[ni * 16 + l15];
    #pragma unroll
    for (int mi = 0; mi < 4; ++mi) {
        int rbase = row0 + wm * 64 + mi * 16 + q * 4;
        #pragma unroll
        for (int ni = 0; ni < 4; ++ni) {
            int cg = col0 + wn * 64 + ni * 16 + l15;
            #pragma unroll
            for (int rg = 0; rg < 4; ++rg) {
                int rr = rbase + rg;
                if (rr < N_V) {
                    float v = acc[mi][ni][rg] + bv[ni];
                    out[(size_t)rr * NOUT + cg] = v > 0.f ? v : 0.f;
                }
            }
        }
    }
}

// ================= fallback: R3 fused kernel (used only if ws too small) =================
__global__ __launch_bounds__(512, 2)
void gemm_fused(const float* __restrict__ bary, const u16* __restrict__ msb,
                const u16* __restrict__ w2, const float* __restrict__ bias,
                float* __restrict__ out) {
    __shared__ u16 At[BM * 64];
    __shared__ u16 Bt[2 * BN * 64];

    const int tid  = threadIdx.x;
    const int lane = tid & 63, wave = tid >> 6;
    const int l15  = lane & 15, q = lane >> 4;
    const int wm   = wave >> 2, wn = wave & 3;

    const int id  = blockIdx.x;
    const int bx  = id % 391, by = id / 391;
    const int row0 = bx * BM, col0 = by * BN;

    const int ar  = tid >> 2;
    const u32 acb = (u32)(tid & 3) * 32;
    int an = row0 + ar; if (an > N_V - 1) an = N_V - 1;
    const u32* brow = (const u32*)bary + (size_t)an * 240;
    const u32 an_off = (u32)an * 128 + acb;

    const int e_a = ar & 7;
    const u32 at_w0 = (u32)ar * 128 + (u32)(((2 * (tid & 3)) ^ e_a) * 16);
    const u32 at_w1 = at_w0 ^ 16;

    const int eq = l15 & 7;
    const u32 a_rd0 = (u32)(wm * 64 + l15) * 128 + (u32)((q ^ eq) * 16);
    const u32 b_rd0 = (u32)(wn * 64 + l15) * 128 + (u32)((q ^ eq) * 16);

    const int rl = lane >> 3;
    const int bl = (lane & 7) ^ rl;

    v4f acc[4][4];
    #pragma unroll
    for (int mi = 0; mi < 4; ++mi)
        #pragma unroll
        for (int ni = 0; ni < 4; ++ni)
            acc[mi][ni] = (v4f){0.f, 0.f, 0.f, 0.f};

    v4u G0_0a, G0_0b, G0_1a, G0_1b, G0_2a, G0_2b;
    v4u G1_0a, G1_0b, G1_1a, G1_1b, G1_2a, G1_2b;
    v4u B0lo, B0hi, B1lo, B1hi;
    float w00, w01, w02, w10, w11, w12;
    v4u cv0, cv1;

#define BARY_LOAD(DLO, DHI, kc) do { \
    u32 _d0 = ((u32)((kc) * 6)) & ~3u; \
    DLO = *(const v4u*)(brow + _d0); \
    DHI = *(const v4u*)(brow + _d0 + 4); } while (0)

#define DECODE_ISSUE(PAR, BLO, BHI, Ga0, Gb0, Ga1, Gb1, Ga2, Gb2, W0, W1, W2) do { \
    u32 uf0, uw0, uf1, uw1, uf2, uw2; \
    if (PAR) { uf0 = BLO[2]; uw0 = BLO[3]; uf1 = BHI[0]; uw1 = BHI[1]; uf2 = BHI[2]; uw2 = BHI[3]; } \
    else     { uf0 = BLO[0]; uw0 = BLO[1]; uf1 = BLO[2]; uw1 = BLO[3]; uf2 = BHI[0]; uw2 = BHI[1]; } \
    u32 _o0 = ((u32)(int)__uint_as_float(uf0) << 7) + acb; \
    u32 _o1 = ((u32)(int)__uint_as_float(uf1) << 7) + acb; \
    u32 _o2 = ((u32)(int)__uint_as_float(uf2) << 7) + acb; \
    const char* _mb = (const char*)msb; \
    Ga0 = *(const v4u*)(_mb + _o0); Gb0 = *(const v4u*)(_mb + _o0 + 16); \
    Ga1 = *(const v4u*)(_mb + _o1); Gb1 = *(const v4u*)(_mb + _o1 + 16); \
    Ga2 = *(const v4u*)(_mb + _o2); Gb2 = *(const v4u*)(_mb + _o2 + 16); \
    W0 = __uint_as_float(uw0); W1 = __uint_as_float(uw1); W2 = __uint_as_float(uw2); } while (0)

#define CONVERT(Ga0, Gb0, Ga1, Gb1, Ga2, Gb2, W0, W1, W2) do { \
    _Pragma("unroll") \
    for (int _j = 0; _j < 4; ++_j) { \
        cv0[_j] = ipair(Ga0[_j], Ga1[_j], Ga2[_j], W0, W1, W2); \
        cv1[_j] = ipair(Gb0[_j], Gb1[_j], Gb2[_j], W0, W1, W2); } } while (0)

#define BLDS(KB_LD, BUF) do { \
    _Pragma("unroll") \
    for (int _ii = 0; _ii < 4; ++_ii) { \
        int _we = wave * 4 + _ii; \
        u32 _src = (u32)(col0 + _we * 8 + rl) * KTOT + (u32)(KB_LD) * 64 + (u32)(bl * 8); \
        gl2lds(w2 + _src, &Bt[(BUF) * (BN * 64) + _we * 512]); } } while (0)

#define AT_STORE() do { \
    *(v4u*)((char*)At + at_w0) = cv0; \
    *(v4u*)((char*)At + at_w1) = cv1; } while (0)

#define MFMA_STEP(BUF) do { \
    const char* _atp = (const char*)At; \
    const char* _btp = (const char*)Bt + (BUF) * (BN * 64 * 2); \
    _Pragma("unroll") \
    for (int _s = 0; _s < 2; ++_s) { \
        u32 _ao = a_rd0 ^ (u32)(_s * 64), _bo = b_rd0 ^ (u32)(_s * 64); \
        v8s _af[4], _bf[4]; \
        _Pragma("unroll") \
        for (int _mi = 0; _mi < 4; ++_mi) _af[_mi] = *(const v8s*)(_atp + _ao + _mi * 2048); \
        _Pragma("unroll") \
        for (int _ni = 0; _ni < 4; ++_ni) _bf[_ni] = *(const v8s*)(_btp + _bo + _ni * 2048); \
        _Pragma("unroll") \
        for (int _mi = 0; _mi < 4; ++_mi) \
            _Pragma("unroll") \
            for (int _ni = 0; _ni < 4; ++_ni) \
                acc[_mi][_ni] = __builtin_amdgcn_mfma_f32_16x16x32_bf16( \
                    _af[_mi], _bf[_ni], acc[_mi][_ni], 0, 0, 0); } } while (0)

#define BAR2_12() asm volatile("s_waitcnt vmcnt(12) lgkmcnt(0)\ns_barrier" ::: "memory")
#define BAR2_10() asm volatile("s_waitcnt vmcnt(10) lgkmcnt(0)\ns_barrier" ::: "memory")
#define BAR2_6()  asm volatile("s_waitcnt vmcnt(6) lgkmcnt(0)\ns_barrier"  ::: "memory")
#define BAR2_4()  asm volatile("s_waitcnt vmcnt(4) lgkmcnt(0)\ns_barrier"  ::: "memory")
#define BAR2_0()  asm volatile("s_waitcnt vmcnt(0) lgkmcnt(0)\ns_barrier"  ::: "memory")
#define BAR1()    asm volatile("s_barrier" ::: "memory")

    BARY_LOAD(B0lo, B0hi, 0);
    DECODE_ISSUE(0, B0lo, B0hi, G0_0a, G0_0b, G0_1a, G0_1b, G0_2a, G0_2b, w00, w01, w02);
    BARY_LOAD(B1lo, B1hi, 1);
    DECODE_ISSUE(1, B1lo, B1hi, G1_0a, G1_0b, G1_1a, G1_1b, G1_2a, G1_2b, w10, w11, w12);
    BARY_LOAD(B0lo, B0hi, 2);
    BLDS(0, 0);

    #pragma unroll 1
    for (int i = 0; i < 20; ++i) {
        {
            const int kb = 2 * i;
            CONVERT(G0_0a, G0_0b, G0_1a, G0_1b, G0_2a, G0_2b, w00, w01, w02);
            if (kb <= 36) BARY_LOAD(B1lo, B1hi, kb + 3);
            if (kb <= 37) {
                DECODE_ISSUE(0, B0lo, B0hi, G0_0a, G0_0b, G0_1a, G0_1b, G0_2a, G0_2b,
                             w00, w01, w02);
            } else if (kb == 38) {
                G0_0a = *(const v4u*)((const char*)msb + an_off);
                G0_0b = *(const v4u*)((const char*)msb + an_off + 16);
            }
            BAR1();
            BLDS(kb + 1, 1);
            AT_STORE();
            if (kb <= 36) BAR2_12(); else BAR2_6();
            MFMA_STEP(0);
        }
        {
            const int kb = 2 * i + 1;
            CONVERT(G1_0a, G1_0b, G1_1a, G1_1b, G1_2a, G1_2b, w10, w11, w12);
            if (kb <= 36) BARY_LOAD(B0lo, B0hi, kb + 3);
            if (kb <= 37)
                DECODE_ISSUE(1, B1lo, B1hi, G1_0a, G1_0b, G1_1a, G1_1b, G1_2a, G1_2b,
                             w10, w11, w12);
            BAR1();
            BLDS(kb + 1, 0);
            AT_STORE();
            if (kb <= 36) BAR2_12();
            else if (kb == 37) BAR2_10();
            else BAR2_4();
            MFMA_STEP(1);
        }
    }
    {
        cv0 = G0_0a; cv1 = G0_0b;
        BAR1();
        AT_STORE();
        BAR2_0();
        MFMA_STEP(0);
    }

    float bv[4];
    #pragma unroll
    for (int ni = 0; ni < 4; ++ni) bv[ni] = bias[ni * 16 + l15];
    #pragma unroll
    for (int mi = 0; mi < 4; ++mi) {
        int rbase = row0 + wm * 64 + mi * 16 + q * 4;
        #pragma unroll
        for (int ni = 0; ni < 4; ++ni) {
            int cg = col0 + wn * 64 + ni * 16 + l15;
            #pragma unroll
            for (int rg = 0; rg < 4; ++rg) {
                int rr = rbase + rg;
                if (rr < N_V) {
                    float v = acc[mi][ni][rg] + bv[ni];
                    out[(size_t)rr * NOUT + cg] = v > 0.f ? v : 0.f;
                }
            }
        }
    }
}

extern "C" void kernel_launch(void* const* d_in, const int* in_sizes, int n_in,
                              void* d_out, int out_size, void* d_ws, size_t ws_size,
                              hipStream_t stream) {
    const float* ms    = (const float*)d_in[0];
    const float* bary  = (const float*)d_in[1];
    const float* nw    = (const float*)d_in[2];
    const float* cw    = (const float*)d_in[3];
    const float* bias  = (const float*)d_in[4];
    const float* coeff = (const float*)d_in[5];
    float* out = (float*)d_out;

    u16* msb = (u16*)d_ws;                        // 6,400,000 B
    u16* w2  = (u16*)((char*)d_ws + 6400000);     // 2,686,976 B
    const size_t x_off  = 9087104;                // 128-aligned
    const size_t x_need = x_off + (size_t)N_V * KTOT * 2;   // + 262,400,000 B
    u16* X = (u16*)((char*)d_ws + x_off);

    if (ws_size >= x_need) {
        cast_ms<<<3125, 256, 0, stream>>>(ms, msb, X);
        build_w2<<<(NOUT * KTOT + 255) / 256, 256, 0, stream>>>(nw, cw, coeff, w2);
        build_x<<<31250, 256, 0, stream>>>(bary, msb, X);
        gemm2<<<784, 512, 0, stream>>>(X, w2, bias, out);
    } else {
        cast_ms<<<3125, 256, 0, stream>>>(ms, msb, (u16*)nullptr);
        build_w2<<<(NOUT * KTOT + 255) / 256, 256, 0, stream>>>(nw, cw, coeff, w2);
        gemm_fused<<<782, 512, 0, stream>>>(bary, msb, w2, bias, out);
    }
}